// Round 12
// baseline (231.756 us; speedup 1.0000x reference)
//
#include <hip/hip_runtime.h>

typedef unsigned short u16;
typedef unsigned int u32;
typedef __bf16 bf16x8 __attribute__((ext_vector_type(8)));
typedef unsigned short u16x8 __attribute__((ext_vector_type(8)));
typedef float f32x4 __attribute__((ext_vector_type(4)));

// XOR swizzle key for [row][64] bf16 LDS tiles (GEMM), 16B chunk granularity.
#define KEY(r) ((((r) ^ ((r) >> 3)) & 7) << 3)
// attn LDS pitches: Ks [128][GPK], Vt [64][GPV], Pl pitch PLP u32
#define GPK 72
#define GPV 136
#define PLP 65
#define VKEY(d) ((((d) >> 3) & 7) << 3)

static __device__ __forceinline__ u16 f2b(float f) {
  union { float f; unsigned u; } x; x.f = f;
  unsigned r = x.u + 0x7FFFu + ((x.u >> 16) & 1u);  // RNE
  return (u16)(r >> 16);
}

static __device__ __forceinline__ bf16x8 ld_frag(const u16* p) {
  union { u16x8 s; bf16x8 b; } u;
  u.s = *reinterpret_cast<const u16x8*>(p);
  return u.b;
}

// ---------------- fused f32 -> bf16 convert (1 dispatch, 4 segments) --------
__global__ __launch_bounds__(256) void cvt_all(
    const float* __restrict__ x, const float* __restrict__ Wq,
    const float* __restrict__ Wkv, const float* __restrict__ Wo,
    u16* __restrict__ xb, u16* __restrict__ wqb,
    u16* __restrict__ wkvb, u16* __restrict__ wob) {
  const int i = blockIdx.x * 256 + threadIdx.x;  // float4 index, 2097152 total
  const float* in; u16* out; int base;
  if (i < 1048576)      { in = x;   out = xb;   base = 0; }
  else if (i < 1310720) { in = Wq;  out = wqb;  base = 1048576; }
  else if (i < 1835008) { in = Wkv; out = wkvb; base = 1310720; }
  else                  { in = Wo;  out = wob;  base = 1835008; }
  const int j = i - base;
  float4 v = reinterpret_cast<const float4*>(in)[j];
  ushort4 o;
  o.x = f2b(v.x); o.y = f2b(v.y); o.z = f2b(v.z); o.w = f2b(v.w);
  reinterpret_cast<ushort4*>(out)[j] = o;
}

// ---------------- GEMM body: 128xBN tile, BK=64 (unchanged) -----------------
template <bool OUT_BF16, int BN>   // BN in {64,128}
static __device__ __forceinline__ void gemm_body(
    const u16* __restrict__ A, const u16* __restrict__ Bt,
    const float* __restrict__ bias, void* __restrict__ outp,
    int N, int K, int row0, int col0, float scale) {
  constexpr int NF = BN / 32;
  __shared__ alignas(16) u16 As[128 * 64];
  __shared__ alignas(16) u16 Bs[BN * 64];
  const int tid = threadIdx.x, wid = tid >> 6, lane = tid & 63;
  const int wr = wid >> 1, wc = wid & 1;
  const int lr = lane >> 3;
  const int lc = (lane & 7) * 8;
  const int frow = lane & 15, fk = (lane >> 4) * 8;
  f32x4 acc[4][NF] = {};

  for (int k0 = 0; k0 < K; k0 += 64) {
    __syncthreads();
#pragma unroll
    for (int t = 0; t < 4; ++t) {
      const int r = wid * 32 + t * 8 + lr;
      __builtin_amdgcn_global_load_lds(
          (const __attribute__((address_space(1))) unsigned int*)(
              A + (size_t)(row0 + r) * K + k0 + (lc ^ KEY(r))),
          (__attribute__((address_space(3))) unsigned int*)(As + (wid * 32 + t * 8) * 64),
          16, 0, 0);
    }
#pragma unroll
    for (int t = 0; t < NF; ++t) {
      const int r = wid * (BN / 4) + t * 8 + lr;
      __builtin_amdgcn_global_load_lds(
          (const __attribute__((address_space(1))) unsigned int*)(
              Bt + (size_t)(col0 + r) * K + k0 + (lc ^ KEY(r))),
          (__attribute__((address_space(3))) unsigned int*)(Bs + (wid * (BN / 4) + t * 8) * 64),
          16, 0, 0);
    }
    __syncthreads();
#pragma unroll
    for (int ks = 0; ks < 2; ++ks) {
      bf16x8 a[4], b[NF];
#pragma unroll
      for (int m = 0; m < 4; ++m) {
        const int r = wr * 64 + m * 16 + frow;
        a[m] = ld_frag(&As[r * 64 + ((ks * 32 + fk) ^ KEY(r))]);
      }
#pragma unroll
      for (int n = 0; n < NF; ++n) {
        const int r = wc * (BN / 2) + n * 16 + frow;
        b[n] = ld_frag(&Bs[r * 64 + ((ks * 32 + fk) ^ KEY(r))]);
      }
#pragma unroll
      for (int m = 0; m < 4; ++m)
#pragma unroll
        for (int n = 0; n < NF; ++n)
          acc[m][n] = __builtin_amdgcn_mfma_f32_16x16x32_bf16(a[m], b[n], acc[m][n], 0, 0, 0);
    }
  }
  const int colL = lane & 15, rb = (lane >> 4) * 4;
#pragma unroll
  for (int n = 0; n < NF; ++n) {
    const int gc = col0 + wc * (BN / 2) + n * 16 + colL;
    const float bv = bias[gc];
#pragma unroll
    for (int m = 0; m < 4; ++m)
#pragma unroll
      for (int r = 0; r < 4; ++r) {
        const int gr = row0 + wr * 64 + m * 16 + rb + r;
        const float v = (acc[m][n][r] + bv) * scale;
        if constexpr (OUT_BF16)
          reinterpret_cast<u16*>(outp)[(size_t)gr * N + gc] = f2b(v);
        else
          reinterpret_cast<float*>(outp)[(size_t)gr * N + gc] = v;
      }
  }
}

__global__ __launch_bounds__(256) void gemm_qkv(
    const u16* __restrict__ xb, const u16* __restrict__ wqb,
    const u16* __restrict__ wkvb, const float* __restrict__ bq,
    const float* __restrict__ bkv, u16* __restrict__ qb, u16* __restrict__ kvb) {
  const int row0 = blockIdx.x * 128;
  const int by = blockIdx.y;
  const u16* Bt; const float* bias; u16* out; int N, col0; float scale;
  if (by < 8) { Bt = wqb;  bias = bq;  out = qb;  N = 1024; col0 = by * 128;      scale = 0.125f; }
  else        { Bt = wkvb; bias = bkv; out = kvb; N = 2048; col0 = (by - 8) * 128; scale = 1.0f; }
  gemm_body<true, 128>(xb, Bt, bias, out, N, 1024, row0, col0, scale);
}

__global__ __launch_bounds__(256) void gemm_o(
    const u16* __restrict__ yb, const u16* __restrict__ wob,
    const float* __restrict__ bo, float* __restrict__ out) {
  gemm_body<false, 64>(yb, wob, bo, out, 1024, 1024, blockIdx.x * 128, blockIdx.y * 64, 1.0f);
}

// ---------------- Flash attention: swapped QK^T, KVBLK=128 ------------------
// grid (B*H, 32), qt = 31-blockIdx.y (LPT). block 256 (4 waves), wave w owns
// q rows [qBase+16w, +16). S^T = mfma(K,Q): lane owns q-column qc=lane&15 with
// 32 k-values in regs; in-register softmax (2 shfl); P packed to LDS b64,
// read back b128 A-frags. Per-tile fixed costs (barriers, rescale, reduce)
// amortized over 128 keys.
__global__ __launch_bounds__(256) void attn_kernel(
    const u16* __restrict__ qb,   // [B*T,1024] bf16, pre-scaled by 1/8
    const u16* __restrict__ kvb,  // [B*T,2048] bf16 (k: h*64, v: 1024+h*64)
    u16* __restrict__ yb,         // [B*T,1024] bf16
    int T) {
  const int C = 1024;
  const int bh = blockIdx.x;
  const int qt = (int)gridDim.y - 1 - (int)blockIdx.y;
  const int b = bh >> 4, h = bh & 15;
  const float slope = (float)(h + 1) * 0.0625f;
  const int tid = threadIdx.x, wid = tid >> 6, lane = tid & 63;
  const int qBase = qt * 64;

  __shared__ alignas(16) u16 Ks[128 * GPK];   // K[k][d]
  __shared__ alignas(16) u16 Vt[64 * GPV];    // V^T: Vt[d][k ^ VKEY(d)]
  __shared__ alignas(16) u32 Pl[4][16 * PLP]; // per-wave P pairs

  const int qc = lane & 15;        // q-column this lane owns
  const int g  = lane >> 4;        // k-subgroup 0..3
  const int g4 = g * 4;
  const int fk = g * 8;

  // Q fragments (loop-invariant): B-operand, row = qc
  const int q_row = qBase + wid * 16 + qc;
  const u16* qp = qb + (size_t)(b * T + q_row) * C + h * 64;
  const bf16x8 aq0 = ld_frag(qp + fk);
  const bf16x8 aq1 = ld_frag(qp + 32 + fk);
  const int qg = q_row;

  float m_q = -1e30f, l_q = 0.f;
  f32x4 accO[4] = {};

  const int sr = tid >> 3;        // 0..31
  const int sc = (tid & 7) * 8;   // 0..56
  const int kx = VKEY(sc);        // d>>3 == sc>>3 for staged 8-elem chunk

  const int nt = (qt + 2) >> 1;   // 128-wide k-tiles covering [0, qBase+64)

  int4 kreg[4], vreg[4];
#pragma unroll
  for (int t = 0; t < 4; ++t) {  // prologue: tile 0 (rows 0..127)
    const int r = sr + 32 * t;
    const size_t gaddr = (size_t)(b * T + r) * 2048 + h * 64 + sc;
    kreg[t] = *reinterpret_cast<const int4*>(&kvb[gaddr]);
    vreg[t] = *reinterpret_cast<const int4*>(&kvb[gaddr + 1024]);
  }

  for (int kt = 0; kt < nt; ++kt) {
    const int kBase = kt * 128;
    __syncthreads();  // previous iteration's reads of Ks/Vt done
#pragma unroll
    for (int t = 0; t < 4; ++t) {
      const int r = sr + 32 * t;
      *reinterpret_cast<int4*>(&Ks[r * GPK + sc]) = kreg[t];
      const u16* pv = reinterpret_cast<const u16*>(&vreg[t]);
#pragma unroll
      for (int j = 0; j < 8; ++j) {
        const int d = sc + j;
        Vt[d * GPV + (r ^ kx)] = pv[j];
      }
    }
    __syncthreads();
    if (kt + 1 < nt) {  // prefetch next tile into regs
#pragma unroll
      for (int t = 0; t < 4; ++t) {
        const int r = sr + 32 * t;
        const size_t gaddr = (size_t)(b * T + kBase + 128 + r) * 2048 + h * 64 + sc;
        kreg[t] = *reinterpret_cast<const int4*>(&kvb[gaddr]);
        vreg[t] = *reinterpret_cast<const int4*>(&kvb[gaddr + 1024]);
      }
    }

    // S^T = K Q^T: accS[n][r] = S[k=kBase+16n+g4+r][q=qc], n=0..7
    f32x4 accS[8] = {};
#pragma unroll
    for (int n = 0; n < 8; ++n) {
      bf16x8 bk0 = ld_frag(&Ks[(n * 16 + qc) * GPK + fk]);
      accS[n] = __builtin_amdgcn_mfma_f32_16x16x32_bf16(bk0, aq0, accS[n], 0, 0, 0);
      bf16x8 bk1 = ld_frag(&Ks[(n * 16 + qc) * GPK + 32 + fk]);
      accS[n] = __builtin_amdgcn_mfma_f32_16x16x32_bf16(bk1, aq1, accS[n], 0, 0, 0);
    }

    // in-register softmax over the lane's 32 k-values (+ ALiBi + causal)
    float tmax = -1e30f;
#pragma unroll
    for (int n = 0; n < 8; ++n) {
      const int kgn = kBase + n * 16 + g4;
#pragma unroll
      for (int r = 0; r < 4; ++r) {
        const int kg = kgn + r;
        float v = fmaf(slope, (float)kg, accS[n][r]);
        v = (kg > qg) ? -1e30f : v;
        accS[n][r] = v;
        tmax = fmaxf(tmax, v);
      }
    }
    tmax = fmaxf(tmax, __shfl_xor(tmax, 16));
    tmax = fmaxf(tmax, __shfl_xor(tmax, 32));
    const float newm = fmaxf(m_q, tmax);
    const float corr = __expf(m_q - newm);
    m_q = newm;
    float psum = 0.f;
#pragma unroll
    for (int n = 0; n < 8; ++n)
#pragma unroll
      for (int r = 0; r < 4; ++r) {
        const float p = __expf(accS[n][r] - newm);
        accS[n][r] = p;
        psum += p;
      }
    psum += __shfl_xor(psum, 16);
    psum += __shfl_xor(psum, 32);
    l_q = l_q * corr + psum;

    // pack P (bf16 truncate) -> Pl pairs; u32 slot = 8n + 2g + p
    u32* Pw = &Pl[wid][qc * PLP];
#pragma unroll
    for (int n = 0; n < 8; ++n) {
      union { float f; u32 u; } a0, a1, a2, a3;
      a0.f = accS[n][0]; a1.f = accS[n][1]; a2.f = accS[n][2]; a3.f = accS[n][3];
      u32 w0 = (a0.u >> 16) | (a1.u & 0xFFFF0000u);
      u32 w1 = (a2.u >> 16) | (a3.u & 0xFFFF0000u);
      *reinterpret_cast<uint2*>(&Pw[8 * n + 2 * g]) = uint2{w0, w1};
    }

    // rescale accO: corr for q' = g4 + r lives in lane g4+r
    float corr4[4];
#pragma unroll
    for (int r = 0; r < 4; ++r) corr4[r] = __shfl(corr, g4 + r);
#pragma unroll
    for (int n = 0; n < 4; ++n)
#pragma unroll
      for (int r = 0; r < 4; ++r) accO[n][r] *= corr4[r];

    // O += P @ V  (A-frag b128 from Pl; B-frag = Vt rows), ks = 0..3
#pragma unroll
    for (int ks = 0; ks < 4; ++ks) {
      uint4 pv4 = *reinterpret_cast<const uint4*>(&Pl[wid][qc * PLP + 16 * ks + g4]);
      union { uint4 q; u16x8 s; bf16x8 bv; } ap; ap.q = pv4;
#pragma unroll
      for (int n = 0; n < 4; ++n) {
        const int d = n * 16 + qc;
        bf16x8 bv = ld_frag(&Vt[d * GPV + ((ks * 32 + fk) ^ VKEY(d))]);
        accO[n] = __builtin_amdgcn_mfma_f32_16x16x32_bf16(ap.bv, bv, accO[n], 0, 0, 0);
      }
    }
  }

  // normalize + store: accO row q' = g4 + r, col d = n*16 + qc
  float inv4[4];
#pragma unroll
  for (int r = 0; r < 4; ++r) inv4[r] = 1.0f / __shfl(l_q, g4 + r);
#pragma unroll
  for (int r = 0; r < 4; ++r) {
    const int qg2 = qBase + wid * 16 + g4 + r;
    u16* yrow = yb + (size_t)(b * T + qg2) * C + h * 64;
#pragma unroll
    for (int n = 0; n < 4; ++n) yrow[n * 16 + qc] = f2b(accO[n][r] * inv4[r]);
  }
}

extern "C" void kernel_launch(void* const* d_in, const int* in_sizes, int n_in,
                              void* d_out, int out_size, void* d_ws, size_t ws_size,
                              hipStream_t stream) {
  const float* x   = (const float*)d_in[0];
  // d_in[1] = freqs_cis (unused under ALiBi)
  const float* Wq  = (const float*)d_in[2];
  const float* bq  = (const float*)d_in[3];
  const float* Wkv = (const float*)d_in[4];
  const float* bkv = (const float*)d_in[5];
  const float* Wo  = (const float*)d_in[6];
  const float* bo  = (const float*)d_in[7];
  float* out = (float*)d_out;

  const int B = 2, T = 2048, C = 1024;
  const int M = B * T;  // 4096

  char* ws = (char*)d_ws;
  u16* xb   = (u16*)(ws + 0);          // 4096x1024  (8 MiB)
  u16* wqb  = (u16*)(ws + 8388608);    // 1024x1024  (2 MiB)
  u16* wkvb = (u16*)(ws + 10485760);   // 2048x1024  (4 MiB)
  u16* wob  = (u16*)(ws + 14680064);   // 1024x1024  (2 MiB)
  u16* qb   = (u16*)(ws + 16777216);   // 4096x1024  (8 MiB)
  u16* kvb  = (u16*)(ws + 25165824);   // 4096x2048  (16 MiB)
  u16* yb   = (u16*)(ws + 41943040);   // 4096x1024  (8 MiB)

  // all four f32->bf16 converts in one dispatch (2097152 float4s)
  cvt_all<<<8192, 256, 0, stream>>>(x, Wq, Wkv, Wo, xb, wqb, wkvb, wob);

  // fused: q = (x@Wq^T + bq)*0.125 ; kv = x@Wkv^T + bkv
  gemm_qkv<<<dim3(M / 128, 8 + 16), 256, 0, stream>>>(xb, wqb, wkvb, bq, bkv, qb, kvb);
  // flash attention (grid: bh x qtile64, reversed for LPT balance)
  attn_kernel<<<dim3(B * 16, T / 64), 256, 0, stream>>>(qb, kvb, yb, T);
  // out = y @ Wo^T + bo  (f32 out)
  gemm_o<<<dim3(M / 128, C / 64), 256, 0, stream>>>(yb, wob, bo, out);
}